// Round 12
// baseline (1057.397 us; speedup 1.0000x reference)
//
#include <hip/hip_runtime.h>
#include <hip/hip_bf16.h>
#include <cstdint>
#include <cstddef>

#define B_   4
#define N_   16384
#define S_   2048
#define D1_  128
#define D2_  256
#define K0_  384
#define C0_  256
#define C1_  128

typedef __attribute__((ext_vector_type(8))) short bf16x8;
typedef __attribute__((ext_vector_type(4))) float f32x4;

__device__ inline unsigned short f2bf(float f) {
  __hip_bfloat16 h = __float2bfloat16(f);
  return *reinterpret_cast<unsigned short*>(&h);
}

// ---------------- prep: transpose points2 [B][D2][S] -> p2t [B][S][D2] ----------------
__global__ __launch_bounds__(256) void k_transpose(const float* __restrict__ p2,
                                                   float* __restrict__ p2t) {
  __shared__ float tile[64][65];
  const int tid = threadIdx.x;
  const int b = blockIdx.y;
  const int s0 = blockIdx.x * 64;
  for (int ct = 0; ct < 4; ++ct) {
#pragma unroll
    for (int i = 0; i < 16; ++i) {
      const int c = ct * 64 + i * 4 + (tid >> 6);
      const int si = tid & 63;
      tile[si][i * 4 + (tid >> 6)] = p2[((size_t)b * D2_ + c) * S_ + s0 + si];
    }
    __syncthreads();
#pragma unroll
    for (int i = 0; i < 16; ++i) {
      const int si = i * 4 + (tid >> 6);
      const int c = tid & 63;
      p2t[((size_t)b * S_ + s0 + si) * D2_ + ct * 64 + c] = tile[si][c];
    }
    __syncthreads();
  }
}

// ---------------- prep: weights f32 -> bf16, pre-tiled per K-step ----------------
// w0b layout: [12 ksteps][256 out][32 k] bf16 ; w1b: [8][128][32]
__global__ __launch_bounds__(256) void k_cvt_w(const float* __restrict__ w0g,
                                               const float* __restrict__ w1g,
                                               unsigned short* __restrict__ w0b,
                                               unsigned short* __restrict__ w1b) {
  const int t = threadIdx.x;
  for (int kt = 0; kt < 12; ++kt)
    for (int kk = 0; kk < 32; ++kk)
      w0b[kt * 8192 + t * 32 + kk] = f2bf(w0g[(size_t)t * K0_ + kt * 32 + kk]);
  if (t < C1_)
    for (int kt = 0; kt < 8; ++kt)
      for (int kk = 0; kk < 32; ++kk)
        w1b[kt * 4096 + t * 32 + kk] = f2bf(w1g[(size_t)t * C0_ + kt * 32 + kk]);
}

// ---------------- fused: kNN + interp + bf16-MFMA MLP + transposed write ----------
// LDS map (64KB):
//   [0,24576):   phase A = xyz2 f32 [3][2048]; GEMM phase = wlds (20480B, 80B/row pad)
//                + BN tables @20480(sc0),21504(sh0),22528(sc1),23040(sh1)
//   [24576,49152): x_lds bf16 [32 rows][768B], XOR-swz; epilogue2 reuses as ot f32[32][132]
//   [49152,65536): y0_lds bf16 [32 rows][512B], XOR-swz
__global__ __launch_bounds__(256, 2) void k_main(
    const float* __restrict__ xyz1, const float* __restrict__ xyz2,
    const float* __restrict__ points1, const float* __restrict__ p2t,
    const unsigned short* __restrict__ w0b, const unsigned short* __restrict__ w1b,
    const float* __restrict__ b0g, const float* __restrict__ g0g,
    const float* __restrict__ bt0g, const float* __restrict__ rm0g,
    const float* __restrict__ rv0g,
    const float* __restrict__ b1g, const float* __restrict__ g1g,
    const float* __restrict__ bt1g, const float* __restrict__ rm1g,
    const float* __restrict__ rv1g,
    float* __restrict__ out) {
  __shared__ __align__(16) char smem[65536];
  float* s_xyz = (float*)smem;
  float* sc0 = (float*)(smem + 20480);
  float* sh0 = (float*)(smem + 21504);
  float* sc1 = (float*)(smem + 22528);
  float* sh1 = (float*)(smem + 23040);
  char* xl = smem + 24576;
  char* yl = smem + 49152;

  const int tid = threadIdx.x;
  const int bx = blockIdx.x;
  const int b = bx >> 9;            // 512 blocks per batch (N/32)
  const int n0 = (bx & 511) * 32;
  const int lane = tid & 63;
  const int wv = tid >> 6;

  // ---- stage xyz2[b] ----
  {
    const float* x2p = xyz2 + (size_t)b * 3 * S_;
    for (int i = tid; i < 3 * S_; i += 256) s_xyz[i] = x2p[i];
  }
  __syncthreads();
  const float* sx = s_xyz;
  const float* sy = s_xyz + S_;
  const float* sz = s_xyz + 2 * S_;

  // ---- phase A: top3 by XLA-CPU-replicated f32 distance ----
  // s1,s2 = strict mul/add chains (XLA reduce: no contraction);
  // dot = contraction FMA chain: fma(q2,z, fma(q1,y, rn(q0*x)));
  // d = rn(rn(s1+s2) - rn(2*dot)).  Only s2/dot rounding can flip ranks.
  for (int rr = 0; rr < 8; ++rr) {
    const int r = wv * 8 + rr;
    const int n = n0 + r;
    const float* q = xyz1 + ((size_t)b * N_ + n) * 3;
    const float q0 = q[0], q1 = q[1], q2 = q[2];
    const float s1f = __fadd_rn(__fadd_rn(__fmul_rn(q0, q0), __fmul_rn(q1, q1)),
                                __fmul_rn(q2, q2));

    float d0 = 3.4e38f, d1 = 3.4e38f, d2 = 3.4e38f;
    int i0 = 0x7fffffff, i1 = 0x7fffffff, i2 = 0x7fffffff;

    auto lessf = [](float d, int s, float D, int S) {
      return (d < D) || (d == D && s < S);
    };
    auto ins = [&](float d, int s) {
      if (lessf(d, s, d2, i2)) {
        if (lessf(d, s, d1, i1)) {
          d2 = d1; i2 = i1;
          if (lessf(d, s, d0, i0)) { d1 = d0; i1 = i0; d0 = d; i0 = s; }
          else                     { d1 = d;  i1 = s; }
        } else { d2 = d; i2 = s; }
      }
    };

#pragma unroll 4
    for (int j = 0; j < 32; ++j) {
      const int s = lane + (j << 6);
      const float x = sx[s], y = sy[s], z = sz[s];
      const float s2f = __fadd_rn(__fadd_rn(__fmul_rn(x, x), __fmul_rn(y, y)),
                                  __fmul_rn(z, z));
      const float dot = fmaf(q2, z, fmaf(q1, y, __fmul_rn(q0, x)));
      const float d = __fsub_rn(__fadd_rn(s1f, s2f), __fmul_rn(2.0f, dot));
      ins(d, s);
    }
#pragma unroll
    for (int off = 1; off < 64; off <<= 1) {
      const float c0 = __shfl_xor(d0, off);
      const float c1 = __shfl_xor(d1, off);
      const float c2 = __shfl_xor(d2, off);
      const int j0 = __shfl_xor(i0, off);
      const int j1 = __shfl_xor(i1, off);
      const int j2 = __shfl_xor(i2, off);
      ins(c0, j0); ins(c1, j1); ins(c2, j2);
    }

    const float r0 = 1.0f / __fadd_rn(d0, 1e-8f);
    const float r1 = 1.0f / __fadd_rn(d1, 1e-8f);
    const float r2 = 1.0f / __fadd_rn(d2, 1e-8f);
    const float rs = __fadd_rn(__fadd_rn(r0, r1), r2);
    const float w0v = r0 / rs, w1v = r1 / rs, w2v = r2 / rs;

    const float4* gp0 = (const float4*)(p2t + ((size_t)b * S_ + i0) * D2_);
    const float4* gp1 = (const float4*)(p2t + ((size_t)b * S_ + i1) * D2_);
    const float4* gp2 = (const float4*)(p2t + ((size_t)b * S_ + i2) * D2_);
    const float4 v0 = gp0[lane], v1 = gp1[lane], v2 = gp2[lane];
    float4 vi;
    vi.x = v0.x * w0v + v1.x * w1v + v2.x * w2v;
    vi.y = v0.y * w0v + v1.y * w1v + v2.y * w2v;
    vi.z = v0.z * w0v + v1.z * w1v + v2.z * w2v;
    vi.w = v0.w * w0v + v1.w * w1v + v2.w * w2v;

    // write x-tile in bf16, XOR-swizzled row layout [32][768B]
    const int sw = (r & 7) << 4;
    uint2 iw;
    iw.x = (unsigned)f2bf(vi.x) | ((unsigned)f2bf(vi.y) << 16);
    iw.y = (unsigned)f2bf(vi.z) | ((unsigned)f2bf(vi.w) << 16);
    *(uint2*)(xl + r * 768 + ((256 + 8 * lane) ^ sw)) = iw;

    const float2 p1v = ((const float2*)(points1 + ((size_t)b * N_ + n) * D1_))[lane];
    const unsigned pw = (unsigned)f2bf(p1v.x) | ((unsigned)f2bf(p1v.y) << 16);
    *(unsigned*)(xl + r * 768 + ((4 * lane) ^ sw)) = pw;
  }
  __syncthreads();

  // ---- BN fold tables (xyz2 region now dead) ----
  {
    const int o = tid;
    if (o < C0_) {
      const double s = (double)g0g[o] / sqrt((double)rv0g[o] + 1e-5);
      sc0[o] = (float)s;
      sh0[o] = (float)(((double)b0g[o] - (double)rm0g[o]) * s + (double)bt0g[o]);
    }
    if (o < C1_) {
      const double s = (double)g1g[o] / sqrt((double)rv1g[o] + 1e-5);
      sc1[o] = (float)s;
      sh1[o] = (float)(((double)b1g[o] - (double)rm1g[o]) * s + (double)bt1g[o]);
    }
  }

  const int hi16 = lane >> 4;   // 0..3
  const int l15 = lane & 15;
  const int asw = (l15 & 7) << 4;   // row&7 == l15&7 for rows rb*16+l15

  // ---- GEMM1: [32x384]x[384x256] via mfma 16x16x32, wave wv owns cols wv*64..+63 ----
  const int cb = wv * 64;
  f32x4 acc[2][4];
#pragma unroll
  for (int i = 0; i < 2; ++i)
#pragma unroll
    for (int j = 0; j < 4; ++j) acc[i][j] = (f32x4){0.f, 0.f, 0.f, 0.f};

  for (int kt = 0; kt < 12; ++kt) {
    __syncthreads();
    {  // stage W0 K-slab: [256 cols][32 k] bf16 -> wlds rows of 80B (pad)
      const uint4* src = (const uint4*)w0b + kt * 1024 + tid * 4;
#pragma unroll
      for (int i = 0; i < 4; ++i)
        *(uint4*)(smem + tid * 80 + i * 16) = src[i];
    }
    __syncthreads();
    const int aoff = (kt * 64 + hi16 * 16) ^ asw;
    const bf16x8 a0 = *(const bf16x8*)(xl + l15 * 768 + aoff);
    const bf16x8 a1 = *(const bf16x8*)(xl + (16 + l15) * 768 + aoff);
#pragma unroll
    for (int cf = 0; cf < 4; ++cf) {
      const bf16x8 bfr = *(const bf16x8*)(smem + (cb + cf * 16 + l15) * 80 + hi16 * 16);
      acc[0][cf] = __builtin_amdgcn_mfma_f32_16x16x32_bf16(a0, bfr, acc[0][cf], 0, 0, 0);
      acc[1][cf] = __builtin_amdgcn_mfma_f32_16x16x32_bf16(a1, bfr, acc[1][cf], 0, 0, 0);
    }
  }

  // ---- epilogue1: BN+ReLU -> y0 bf16 (swz). D map: col=lane&15, row=(lane>>4)*4+reg ----
#pragma unroll
  for (int rb = 0; rb < 2; ++rb)
#pragma unroll
    for (int cf = 0; cf < 4; ++cf) {
      const int col = cb + cf * 16 + l15;
      const float s = sc0[col], h = sh0[col];
#pragma unroll
      for (int rg = 0; rg < 4; ++rg) {
        const int row = rb * 16 + hi16 * 4 + rg;
        float v = acc[rb][cf][rg] * s + h;
        v = v > 0.f ? v : 0.f;
        *(unsigned short*)(yl + row * 512 + ((col * 2) ^ ((row & 7) << 4))) = f2bf(v);
      }
    }

  // ---- GEMM2: [32x256]x[256x128], wave wv owns cols wv*32..+31 ----
  const int cb2 = wv * 32;
  f32x4 acc2[2][2];
#pragma unroll
  for (int i = 0; i < 2; ++i)
#pragma unroll
    for (int j = 0; j < 2; ++j) acc2[i][j] = (f32x4){0.f, 0.f, 0.f, 0.f};

  for (int kt = 0; kt < 8; ++kt) {
    __syncthreads();   // kt=0: also fences epilogue1 y0 writes + last wlds reads
    if (tid < 128) {
      const uint4* src = (const uint4*)w1b + kt * 512 + tid * 4;
#pragma unroll
      for (int i = 0; i < 4; ++i)
        *(uint4*)(smem + tid * 80 + i * 16) = src[i];
    }
    __syncthreads();
    const int aoff = (kt * 64 + hi16 * 16) ^ asw;
    const bf16x8 a0 = *(const bf16x8*)(yl + l15 * 512 + aoff);
    const bf16x8 a1 = *(const bf16x8*)(yl + (16 + l15) * 512 + aoff);
#pragma unroll
    for (int cf = 0; cf < 2; ++cf) {
      const bf16x8 bfr = *(const bf16x8*)(smem + (cb2 + cf * 16 + l15) * 80 + hi16 * 16);
      acc2[0][cf] = __builtin_amdgcn_mfma_f32_16x16x32_bf16(a0, bfr, acc2[0][cf], 0, 0, 0);
      acc2[1][cf] = __builtin_amdgcn_mfma_f32_16x16x32_bf16(a1, bfr, acc2[1][cf], 0, 0, 0);
    }
  }

  // ---- epilogue2: BN+ReLU -> ot f32 [32][132] (reuses x_lds region), transposed write ----
  float* ot = (float*)xl;
#pragma unroll
  for (int rb = 0; rb < 2; ++rb)
#pragma unroll
    for (int cf = 0; cf < 2; ++cf) {
      const int col = cb2 + cf * 16 + l15;
      const float s = sc1[col], h = sh1[col];
#pragma unroll
      for (int rg = 0; rg < 4; ++rg) {
        const int row = rb * 16 + hi16 * 4 + rg;
        float v = acc2[rb][cf][rg] * s + h;
        ot[row * 132 + col] = v > 0.f ? v : 0.f;
      }
    }
  __syncthreads();
  {
    const size_t ob = (size_t)b * C1_ * N_;
#pragma unroll
    for (int it = 0; it < 16; ++it) {
      const int idx = it * 256 + tid;
      const int o = idx >> 5;
      const int nn = idx & 31;
      out[ob + (size_t)o * N_ + n0 + nn] = ot[nn * 132 + o];
    }
  }
}

// ---------------- launcher ----------------
extern "C" void kernel_launch(void* const* d_in, const int* in_sizes, int n_in,
                              void* d_out, int out_size, void* d_ws, size_t ws_size,
                              hipStream_t stream) {
  const float* xyz1    = (const float*)d_in[0];
  const float* xyz2    = (const float*)d_in[1];
  const float* points1 = (const float*)d_in[2];
  const float* points2 = (const float*)d_in[3];
  const float* w0g  = (const float*)d_in[4];
  const float* b0g  = (const float*)d_in[5];
  const float* g0g  = (const float*)d_in[6];
  const float* bt0g = (const float*)d_in[7];
  const float* rm0g = (const float*)d_in[8];
  const float* rv0g = (const float*)d_in[9];
  const float* w1g  = (const float*)d_in[10];
  const float* b1g  = (const float*)d_in[11];
  const float* g1g  = (const float*)d_in[12];
  const float* bt1g = (const float*)d_in[13];
  const float* rm1g = (const float*)d_in[14];
  const float* rv1g = (const float*)d_in[15];

  // ws layout: [0,196608) w0b bf16; [196608,262144) w1b bf16; [262144, +8.4MB) p2t f32
  unsigned short* w0b = (unsigned short*)d_ws;
  unsigned short* w1b = (unsigned short*)((char*)d_ws + 196608);
  float* p2t = (float*)((char*)d_ws + 262144);

  k_cvt_w<<<1, 256, 0, stream>>>(w0g, w1g, w0b, w1b);
  k_transpose<<<dim3(S_ / 64, B_), 256, 0, stream>>>(points2, p2t);
  k_main<<<dim3(B_ * (N_ / 32)), 256, 0, stream>>>(
      xyz1, xyz2, points1, p2t, w0b, w1b,
      b0g, g0g, bt0g, rm0g, rv0g,
      b1g, g1g, bt1g, rm1g, rv1g,
      (float*)d_out);
}

// Round 13
// 327.608 us; speedup vs baseline: 3.2276x; 3.2276x over previous
//
#include <hip/hip_runtime.h>
#include <hip/hip_bf16.h>
#include <cstdint>
#include <cstddef>

#define B_   4
#define N_   16384
#define S_   2048
#define D1_  128
#define D2_  256
#define K0_  384
#define C0_  256
#define C1_  128

typedef __attribute__((ext_vector_type(8))) short bf16x8;
typedef __attribute__((ext_vector_type(4))) float f32x4;

__device__ inline unsigned short f2bf(float f) {
  __hip_bfloat16 h = __float2bfloat16(f);
  return *reinterpret_cast<unsigned short*>(&h);
}

// ---------------- prep: transpose points2 [B][D2][S] -> p2t [B][S][D2] ----------------
__global__ __launch_bounds__(256) void k_transpose(const float* __restrict__ p2,
                                                   float* __restrict__ p2t) {
  __shared__ float tile[64][65];
  const int tid = threadIdx.x;
  const int b = blockIdx.y;
  const int s0 = blockIdx.x * 64;
  for (int ct = 0; ct < 4; ++ct) {
#pragma unroll
    for (int i = 0; i < 16; ++i) {
      const int c = ct * 64 + i * 4 + (tid >> 6);
      const int si = tid & 63;
      tile[si][i * 4 + (tid >> 6)] = p2[((size_t)b * D2_ + c) * S_ + s0 + si];
    }
    __syncthreads();
#pragma unroll
    for (int i = 0; i < 16; ++i) {
      const int si = i * 4 + (tid >> 6);
      const int c = tid & 63;
      p2t[((size_t)b * S_ + s0 + si) * D2_ + ct * 64 + c] = tile[si][c];
    }
    __syncthreads();
  }
}

// ---------------- prep: weights f32 -> bf16 pre-tiled, parallel over grid ----------------
// w0b: [12 ksteps][256 out][32 k] ; w1b: [8][128][32]
__global__ __launch_bounds__(256) void k_cvt_w(const float* __restrict__ w0g,
                                               const float* __restrict__ w1g,
                                               unsigned short* __restrict__ w0b,
                                               unsigned short* __restrict__ w1b) {
  const int idx = blockIdx.x * 256 + threadIdx.x;
  const int stride = gridDim.x * 256;
  for (int o = idx; o < 256 * K0_; o += stride) {
    const int col = o / K0_, r = o - col * K0_, kt = r >> 5, kk = r & 31;
    w0b[kt * 8192 + col * 32 + kk] = f2bf(w0g[o]);
  }
  for (int o = idx; o < 128 * C0_; o += stride) {
    const int col = o / C0_, r = o - col * C0_, kt = r >> 5, kk = r & 31;
    w1b[kt * 4096 + col * 32 + kk] = f2bf(w1g[o]);
  }
}

// ---------------- fused: kNN + interp + bf16-MFMA MLP + transposed write ----------
// LDS 27648 B -> 5 blocks/CU (20 waves):
//   [0,24576): x_tile bf16 [32][768B] swz (phase A -> GEMM1)
//              epilogue1 overlays y0 bf16 [32][512B] at [0,16384)
//              epilogue2 overlays ot f32 [32][132] at [0,16896)
//   [24576,25600) sc0 | [25600,26624) sh0 | [26624,27136) sc1 | [27136,27648) sh1
__global__ __launch_bounds__(256, 4) void k_main(
    const float* __restrict__ xyz1, const float* __restrict__ xyz2,
    const float* __restrict__ points1, const float* __restrict__ p2t,
    const unsigned short* __restrict__ w0b, const unsigned short* __restrict__ w1b,
    const float* __restrict__ b0g, const float* __restrict__ g0g,
    const float* __restrict__ bt0g, const float* __restrict__ rm0g,
    const float* __restrict__ rv0g,
    const float* __restrict__ b1g, const float* __restrict__ g1g,
    const float* __restrict__ bt1g, const float* __restrict__ rm1g,
    const float* __restrict__ rv1g,
    float* __restrict__ out) {
  __shared__ __align__(16) char smem[27648];
  char* xl = smem;
  char* yl = smem;
  float* sc0 = (float*)(smem + 24576);
  float* sh0 = (float*)(smem + 25600);
  float* sc1 = (float*)(smem + 26624);
  float* sh1 = (float*)(smem + 27136);

  const int tid = threadIdx.x;
  const int bx = blockIdx.x;
  const int b = bx >> 9;            // 512 blocks per batch (N/32)
  const int n0 = (bx & 511) * 32;
  const int lane = tid & 63;
  const int wv = tid >> 6;

  // ---- BN fold tables (independent of phase A) ----
  {
    const int o = tid;
    if (o < C0_) {
      const double s = (double)g0g[o] / sqrt((double)rv0g[o] + 1e-5);
      sc0[o] = (float)s;
      sh0[o] = (float)(((double)b0g[o] - (double)rm0g[o]) * s + (double)bt0g[o]);
    }
    if (o < C1_) {
      const double s = (double)g1g[o] / sqrt((double)rv1g[o] + 1e-5);
      sc1[o] = (float)s;
      sh1[o] = (float)(((double)b1g[o] - (double)rm1g[o]) * s + (double)bt1g[o]);
    }
  }

  // ---- phase A: top3 per row by XLA-CPU-replicated f32 distance ----
  // s1,s2 strict chains; dot FMA chain; d = rn(rn(s1+s2)-rn(2*dot)); lex (d, idx).
  // xyz2 read direct from global (24KB/batch, L1-hot, coalesced float4).
  const float* x2p = xyz2 + (size_t)b * 3 * S_;
  for (int rr = 0; rr < 8; ++rr) {
    const int r = wv * 8 + rr;
    const int n = n0 + r;
    const float* q = xyz1 + ((size_t)b * N_ + n) * 3;
    const float q0 = q[0], q1 = q[1], q2 = q[2];
    const float s1f = __fadd_rn(__fadd_rn(__fmul_rn(q0, q0), __fmul_rn(q1, q1)),
                                __fmul_rn(q2, q2));

    float d0 = 3.4e38f, d1 = 3.4e38f, d2 = 3.4e38f;
    int i0 = 0x7fffffff, i1 = 0x7fffffff, i2 = 0x7fffffff;

    // branchless sorted-3 insert, lex (d, idx); r0=>r1=>r2 by invariant
    auto insB = [&](float d, int s) {
      const bool c2 = (d < d2) || (d == d2 && s < i2);
      const bool c1 = (d < d1) || (d == d1 && s < i1);
      const bool c0 = (d < d0) || (d == d0 && s < i0);
      const float nd2 = c1 ? d1 : (c2 ? d : d2); const int ni2 = c1 ? i1 : (c2 ? s : i2);
      const float nd1 = c0 ? d0 : (c1 ? d : d1); const int ni1 = c0 ? i0 : (c1 ? s : i1);
      const float nd0 = c0 ? d  : d0;            const int ni0 = c0 ? s  : i0;
      d2 = nd2; i2 = ni2; d1 = nd1; i1 = ni1; d0 = nd0; i0 = ni0;
    };

#pragma unroll 2
    for (int j4 = 0; j4 < 8; ++j4) {
      const int sbase = j4 * 256 + 4 * lane;
      const float4 xv = *(const float4*)(x2p + sbase);
      const float4 yv = *(const float4*)(x2p + 2048 + sbase);
      const float4 zv = *(const float4*)(x2p + 4096 + sbase);
#pragma unroll
      for (int c = 0; c < 4; ++c) {
        const float x = (c == 0) ? xv.x : (c == 1) ? xv.y : (c == 2) ? xv.z : xv.w;
        const float y = (c == 0) ? yv.x : (c == 1) ? yv.y : (c == 2) ? yv.z : yv.w;
        const float z = (c == 0) ? zv.x : (c == 1) ? zv.y : (c == 2) ? zv.z : zv.w;
        const float s2f = __fadd_rn(__fadd_rn(__fmul_rn(x, x), __fmul_rn(y, y)),
                                    __fmul_rn(z, z));
        const float dot = fmaf(q2, z, fmaf(q1, y, __fmul_rn(q0, x)));
        const float d = __fsub_rn(__fadd_rn(s1f, s2f), __fmul_rn(2.0f, dot));
        insB(d, sbase + c);
      }
    }
    // butterfly merge of sorted (d, idx) triples across 64 lanes
#pragma unroll
    for (int off = 1; off < 64; off <<= 1) {
      const float c0 = __shfl_xor(d0, off);
      const float c1 = __shfl_xor(d1, off);
      const float c2 = __shfl_xor(d2, off);
      const int j0 = __shfl_xor(i0, off);
      const int j1 = __shfl_xor(i1, off);
      const int j2 = __shfl_xor(i2, off);
      insB(c0, j0); insB(c1, j1); insB(c2, j2);
    }

    const float r0 = 1.0f / __fadd_rn(d0, 1e-8f);
    const float r1 = 1.0f / __fadd_rn(d1, 1e-8f);
    const float r2 = 1.0f / __fadd_rn(d2, 1e-8f);
    const float rs = __fadd_rn(__fadd_rn(r0, r1), r2);
    const float w0v = r0 / rs, w1v = r1 / rs, w2v = r2 / rs;

    const float4* gp0 = (const float4*)(p2t + ((size_t)b * S_ + i0) * D2_);
    const float4* gp1 = (const float4*)(p2t + ((size_t)b * S_ + i1) * D2_);
    const float4* gp2 = (const float4*)(p2t + ((size_t)b * S_ + i2) * D2_);
    const float4 v0 = gp0[lane], v1 = gp1[lane], v2 = gp2[lane];
    float4 vi;
    vi.x = v0.x * w0v + v1.x * w1v + v2.x * w2v;
    vi.y = v0.y * w0v + v1.y * w1v + v2.y * w2v;
    vi.z = v0.z * w0v + v1.z * w1v + v2.z * w2v;
    vi.w = v0.w * w0v + v1.w * w1v + v2.w * w2v;

    // x-tile bf16, XOR-swizzled rows [32][768B]
    const int sw = (r & 7) << 4;
    uint2 iw;
    iw.x = (unsigned)f2bf(vi.x) | ((unsigned)f2bf(vi.y) << 16);
    iw.y = (unsigned)f2bf(vi.z) | ((unsigned)f2bf(vi.w) << 16);
    *(uint2*)(xl + r * 768 + ((256 + 8 * lane) ^ sw)) = iw;

    const float2 p1v = ((const float2*)(points1 + ((size_t)b * N_ + n) * D1_))[lane];
    const unsigned pw = (unsigned)f2bf(p1v.x) | ((unsigned)f2bf(p1v.y) << 16);
    *(unsigned*)(xl + r * 768 + ((4 * lane) ^ sw)) = pw;
  }
  __syncthreads();   // B1: x-tile + BN ready

  const int hi16 = lane >> 4;
  const int l15 = lane & 15;
  const int asw = (l15 & 7) << 4;

  // ---- GEMM1: [32x384]x[384x256]; A from LDS, B direct from L2-hot w0b; no inner barriers ----
  const int cb = wv * 64;
  f32x4 acc[2][4];
#pragma unroll
  for (int i = 0; i < 2; ++i)
#pragma unroll
    for (int j = 0; j < 4; ++j) acc[i][j] = (f32x4){0.f, 0.f, 0.f, 0.f};

#pragma unroll 2
  for (int kt = 0; kt < 12; ++kt) {
    const int aoff = (kt * 64 + hi16 * 16) ^ asw;
    const bf16x8 a0 = *(const bf16x8*)(xl + l15 * 768 + aoff);
    const bf16x8 a1 = *(const bf16x8*)(xl + (16 + l15) * 768 + aoff);
#pragma unroll
    for (int cf = 0; cf < 4; ++cf) {
      const bf16x8 bfr = *(const bf16x8*)(w0b + kt * 8192 + (cb + cf * 16 + l15) * 32 + hi16 * 8);
      acc[0][cf] = __builtin_amdgcn_mfma_f32_16x16x32_bf16(a0, bfr, acc[0][cf], 0, 0, 0);
      acc[1][cf] = __builtin_amdgcn_mfma_f32_16x16x32_bf16(a1, bfr, acc[1][cf], 0, 0, 0);
    }
  }
  __syncthreads();   // B2: all x reads done before y0 overlay

  // ---- epilogue1: BN+ReLU -> y0 bf16 swz (overlays x region). D: col=lane&15, row=(lane>>4)*4+reg ----
#pragma unroll
  for (int rb = 0; rb < 2; ++rb)
#pragma unroll
    for (int cf = 0; cf < 4; ++cf) {
      const int col = cb + cf * 16 + l15;
      const float s = sc0[col], h = sh0[col];
#pragma unroll
      for (int rg = 0; rg < 4; ++rg) {
        const int row = rb * 16 + hi16 * 4 + rg;
        float v = acc[rb][cf][rg] * s + h;
        v = v > 0.f ? v : 0.f;
        *(unsigned short*)(yl + row * 512 + ((col * 2) ^ ((row & 7) << 4))) = f2bf(v);
      }
    }
  __syncthreads();   // B3: y0 ready

  // ---- GEMM2: [32x256]x[256x128]; A from y0 LDS, B direct from w1b ----
  const int cb2 = wv * 32;
  f32x4 acc2[2][2];
#pragma unroll
  for (int i = 0; i < 2; ++i)
#pragma unroll
    for (int j = 0; j < 2; ++j) acc2[i][j] = (f32x4){0.f, 0.f, 0.f, 0.f};

#pragma unroll 2
  for (int kt = 0; kt < 8; ++kt) {
    const int aoff = (kt * 64 + hi16 * 16) ^ asw;
    const bf16x8 a0 = *(const bf16x8*)(yl + l15 * 512 + aoff);
    const bf16x8 a1 = *(const bf16x8*)(yl + (16 + l15) * 512 + aoff);
#pragma unroll
    for (int cf = 0; cf < 2; ++cf) {
      const bf16x8 bfr = *(const bf16x8*)(w1b + kt * 4096 + (cb2 + cf * 16 + l15) * 32 + hi16 * 8);
      acc2[0][cf] = __builtin_amdgcn_mfma_f32_16x16x32_bf16(a0, bfr, acc2[0][cf], 0, 0, 0);
      acc2[1][cf] = __builtin_amdgcn_mfma_f32_16x16x32_bf16(a1, bfr, acc2[1][cf], 0, 0, 0);
    }
  }
  __syncthreads();   // B4: y0 reads done before ot overlay

  // ---- epilogue2: BN+ReLU -> ot f32 [32][132] (overlay), transposed coalesced write ----
  float* ot = (float*)smem;
#pragma unroll
  for (int rb = 0; rb < 2; ++rb)
#pragma unroll
    for (int cf = 0; cf < 2; ++cf) {
      const int col = cb2 + cf * 16 + l15;
      const float s = sc1[col], h = sh1[col];
#pragma unroll
      for (int rg = 0; rg < 4; ++rg) {
        const int row = rb * 16 + hi16 * 4 + rg;
        float v = acc2[rb][cf][rg] * s + h;
        ot[row * 132 + col] = v > 0.f ? v : 0.f;
      }
    }
  __syncthreads();   // B5: ot ready
  {
    const size_t ob = (size_t)b * C1_ * N_;
#pragma unroll
    for (int it = 0; it < 16; ++it) {
      const int idx = it * 256 + tid;
      const int o = idx >> 5;
      const int nn = idx & 31;
      out[ob + (size_t)o * N_ + n0 + nn] = ot[nn * 132 + o];
    }
  }
}

// ---------------- launcher ----------------
extern "C" void kernel_launch(void* const* d_in, const int* in_sizes, int n_in,
                              void* d_out, int out_size, void* d_ws, size_t ws_size,
                              hipStream_t stream) {
  const float* xyz1    = (const float*)d_in[0];
  const float* xyz2    = (const float*)d_in[1];
  const float* points1 = (const float*)d_in[2];
  const float* points2 = (const float*)d_in[3];
  const float* w0g  = (const float*)d_in[4];
  const float* b0g  = (const float*)d_in[5];
  const float* g0g  = (const float*)d_in[6];
  const float* bt0g = (const float*)d_in[7];
  const float* rm0g = (const float*)d_in[8];
  const float* rv0g = (const float*)d_in[9];
  const float* w1g  = (const float*)d_in[10];
  const float* b1g  = (const float*)d_in[11];
  const float* g1g  = (const float*)d_in[12];
  const float* bt1g = (const float*)d_in[13];
  const float* rm1g = (const float*)d_in[14];
  const float* rv1g = (const float*)d_in[15];

  // ws layout: [0,196608) w0b bf16; [196608,262144) w1b bf16; [262144, +8.4MB) p2t f32
  unsigned short* w0b = (unsigned short*)d_ws;
  unsigned short* w1b = (unsigned short*)((char*)d_ws + 196608);
  float* p2t = (float*)((char*)d_ws + 262144);

  k_cvt_w<<<128, 256, 0, stream>>>(w0g, w1g, w0b, w1b);
  k_transpose<<<dim3(S_ / 64, B_), 256, 0, stream>>>(points2, p2t);
  k_main<<<dim3(B_ * (N_ / 32)), 256, 0, stream>>>(
      xyz1, xyz2, points1, p2t, w0b, w1b,
      b0g, g0g, bt0g, rm0g, rv0g,
      b1g, g1g, bt1g, rm1g, rv1g,
      (float*)d_out);
}